// Round 9
// baseline (397.626 us; speedup 1.0000x reference)
//
#include <hip/hip_runtime.h>

// Problem constants
#define NTOK 65536          // B*S tokens
#define DDIM 64             // embedding dim
#define KCB  4096           // codebook size
#define MB   128            // tokens per block
#define NCH  128            // codes per staged chunk
#define NCHUNKS (KCB / NCH) // 32
#define ESTR 72             // padded LDS row stride (bf16 elems); 144B rows, 16B-aligned
#define LCAP 6144           // candidate capacity (expect ~1K with lagged threshold)
#define WWIN 8.0e-5f        // >= 2*(ulp(z2+e2<128)+ulp(s)+split err) ~ 3.4e-5
#define IDXOFF  (NTOK * DDIM)
#define LOSSOFF (NTOK * DDIM + NTOK)

typedef __bf16 bf16x8 __attribute__((ext_vector_type(8)));
typedef float  f32x4  __attribute__((ext_vector_type(4)));

__device__ __forceinline__ float opaque(float x) { asm volatile("" : "+v"(x)); return x; }

// numpy pairwise sum of squares, n=64
__device__ __forceinline__ float np_sumsq64(const float* __restrict__ v) {
    float r[8];
#pragma unroll
    for (int j = 0; j < 8; ++j) r[j] = opaque(v[j] * v[j]);
#pragma unroll
    for (int i = 1; i < 8; ++i)
#pragma unroll
        for (int j = 0; j < 8; ++j) r[j] += opaque(v[8 * i + j] * v[8 * i + j]);
    return ((r[0] + r[1]) + (r[2] + r[3])) + ((r[4] + r[5]) + (r[6] + r[7]));
}

__device__ __forceinline__ unsigned short bf16rne(float x) {
    unsigned u = __float_as_uint(x);
    return (unsigned short)((u + 0x7fffu + ((u >> 16) & 1u)) >> 16);
}
__device__ __forceinline__ float bf16tof(unsigned short h) {
    return __uint_as_float(((unsigned)h) << 16);
}

// ---- Prep: e2 (np pairwise) + split-bf16 codebook + zero loss ----
__global__ void k_prep(const float* __restrict__ emb, float* __restrict__ e2,
                       unsigned short* __restrict__ eh, unsigned short* __restrict__ el,
                       double* __restrict__ lossacc) {
    int k = blockIdx.x * blockDim.x + threadIdx.x;
    if (k == 0) *lossacc = 0.0;
    if (k >= KCB) return;
    float row[DDIM];
    const float4* r4 = (const float4*)(emb + (size_t)k * DDIM);
#pragma unroll
    for (int i = 0; i < DDIM / 4; ++i) {
        float4 v = r4[i];
        row[4*i+0] = v.x; row[4*i+1] = v.y; row[4*i+2] = v.z; row[4*i+3] = v.w;
    }
    e2[k] = np_sumsq64(row);
#pragma unroll
    for (int j = 0; j < DDIM; ++j) {
        unsigned short h = bf16rne(row[j]);
        unsigned short l = bf16rne(row[j] - bf16tof(h));
        eh[(size_t)k * DDIM + j] = h;
        el[(size_t)k * DDIM + j] = l;
    }
}

// ---- Main: single MFMA sweep in h' = 0.5 + e2 - (2z).e domain + exact rescore ----
// 512 thr = 8 waves; wm = w>>1 (0..3): 32-token group (ms 0..1); wn = w&1: 64-col group.
// A = split-bf16(-2z) in VGPRs whole-kernel; acc init = e2[col]+0.5 (col = lane&15
// is acc-lane-constant) -> MFMA emits h' directly; epilogue = 3 VALU/elem.
// Capture h' <= lagged_min + W (superset of np argmin); exact np-chain rescore.
__global__ __launch_bounds__(512, 2)
void k_vq(const float* __restrict__ z, const float* __restrict__ emb,
          const float* __restrict__ e2g,
          const unsigned short* __restrict__ ehg, const unsigned short* __restrict__ elg,
          float* __restrict__ out, double* __restrict__ lossacc) {
    __shared__ alignas(16) unsigned short esh[NCH * ESTR], esl[NCH * ESTR];  // 36 KB
    __shared__ float e2t[NCH];
    __shared__ float z2s[MB];
    __shared__ unsigned v0u[MB];
    __shared__ unsigned long long keys[MB];
    __shared__ unsigned list[LCAP];          // 24 KB
    __shared__ int lcnt;
    __shared__ float red[512];
    __shared__ int bidx_s[MB];

    const int tid  = threadIdx.x;
    const int lane = tid & 63;
    const int l15  = lane & 15;
    const int quad = lane >> 4;
    const int w    = tid >> 6;
    const int wm   = w >> 1;    // 0..3 : 32-token group
    const int wn   = w & 1;     // 0..1 : 64-col group
    const int tok0 = blockIdx.x * MB;
    const size_t zbase = (size_t)tok0 * DDIM;

    if (tid < MB) { v0u[tid] = 0x7f800000u; keys[tid] = 0xFFFFFFFFFFFFFFFFull; }
    if (tid == 0) lcnt = 0;

    // ---- A-fragments: split bf16 of (-2z), global -> VGPRs (whole-kernel live) ----
    bf16x8 Ah[2][2], Al[2][2];   // [ms][kh]
#pragma unroll
    for (int ms = 0; ms < 2; ++ms) {
        const float* p = z + zbase + (size_t)(wm * 32 + ms * 16 + l15) * DDIM + quad * 8;
#pragma unroll
        for (int kh = 0; kh < 2; ++kh) {
            float4 u0 = *(const float4*)(p + kh * 32);
            float4 u1 = *(const float4*)(p + kh * 32 + 4);
            float d[8] = {-(u0.x + u0.x), -(u0.y + u0.y), -(u0.z + u0.z), -(u0.w + u0.w),
                          -(u1.x + u1.x), -(u1.y + u1.y), -(u1.z + u1.z), -(u1.w + u1.w)};
            union { bf16x8 v; unsigned short u[8]; } th, tl;
#pragma unroll
            for (int j = 0; j < 8; ++j) {
                unsigned short h = bf16rne(d[j]);
                th.u[j] = h;
                tl.u[j] = bf16rne(d[j] - bf16tof(h));
            }
            Ah[ms][kh] = th.v;
            Al[ms][kh] = tl.v;
        }
    }

    // z2 per token (exact np pairwise) — used only by the exact rescore
    if (tid < MB) {
        float row[DDIM];
        const float4* zr4 = (const float4*)(z + zbase + (size_t)tid * DDIM);
#pragma unroll
        for (int i = 0; i < DDIM / 4; ++i) {
            float4 v = zr4[i];
            row[4*i+0] = v.x; row[4*i+1] = v.y; row[4*i+2] = v.z; row[4*i+3] = v.w;
        }
        z2s[tid] = np_sumsq64(row);
    }

    // ---- stage chunk 0 (16B copies: 1024 uint4 slots = 128 rows x 8) ----
#pragma unroll
    for (int it = 0; it < 2; ++it) {
        int g = it * 512 + tid, rr = g >> 3, c8 = g & 7;
        *(uint4*)(&esh[rr * ESTR + c8 * 8]) = ((const uint4*)(ehg + (size_t)rr * DDIM))[c8];
        *(uint4*)(&esl[rr * ESTR + c8 * 8]) = ((const uint4*)(elg + (size_t)rr * DDIM))[c8];
    }
    if (tid < NCH) e2t[tid] = e2g[tid];
    __syncthreads();

    float hrun[8], thr[8];
#pragma unroll
    for (int i = 0; i < 8; ++i) { hrun[i] = 3.0e38f; thr[i] = 3.0e38f; }

    auto mfma_chunk = [&](int n0, bool append) {
#pragma unroll
        for (int ns = 0; ns < 4; ++ns) {
            int nl = wn * 64 + ns * 16 + l15;
            const unsigned short* pb = &esh[nl * ESTR + quad * 8];
            const unsigned short* pc = &esl[nl * ESTR + quad * 8];
            bf16x8 Bh0 = *(const bf16x8*)pb;
            bf16x8 Bh1 = *(const bf16x8*)(pb + 32);
            bf16x8 Bl0 = *(const bf16x8*)pc;
            bf16x8 Bl1 = *(const bf16x8*)(pc + 32);
            float c0 = e2t[nl] + 0.5f;     // acc-lane-constant (col = l15)
            int   n  = n0 + nl;
#pragma unroll
            for (int ms = 0; ms < 2; ++ms) {
                f32x4 a0 = {c0, c0, c0, c0}, a1 = {0.f, 0.f, 0.f, 0.f};
                a0 = __builtin_amdgcn_mfma_f32_16x16x32_bf16(Ah[ms][0], Bh0, a0, 0, 0, 0);
                a1 = __builtin_amdgcn_mfma_f32_16x16x32_bf16(Ah[ms][1], Bh1, a1, 0, 0, 0);
                a0 = __builtin_amdgcn_mfma_f32_16x16x32_bf16(Ah[ms][0], Bl0, a0, 0, 0, 0);
                a1 = __builtin_amdgcn_mfma_f32_16x16x32_bf16(Ah[ms][1], Bl1, a1, 0, 0, 0);
                a0 = __builtin_amdgcn_mfma_f32_16x16x32_bf16(Al[ms][0], Bh0, a0, 0, 0, 0);
                a1 = __builtin_amdgcn_mfma_f32_16x16x32_bf16(Al[ms][1], Bh1, a1, 0, 0, 0);
#pragma unroll
                for (int r = 0; r < 4; ++r) {
                    int i = ms * 4 + r;
                    float h = a0[r] + a1[r];           // h' = 0.5 + e2 - m~
                    if (append && h <= thr[i]) {
                        int m = wm * 32 + ms * 16 + quad * 4 + r;
                        int idx = atomicAdd(&lcnt, 1);
                        if (idx < LCAP) list[idx] = ((unsigned)m << 12) | (unsigned)n;
                    }
                    hrun[i] = fminf(hrun[i], h);
                }
            }
        }
    };
    auto v0_commit = [&]() {
#pragma unroll
        for (int i = 0; i < 8; ++i) {
            float v = hrun[i];
            v = fminf(v, __shfl_xor(v, 1));
            v = fminf(v, __shfl_xor(v, 2));
            v = fminf(v, __shfl_xor(v, 4));
            v = fminf(v, __shfl_xor(v, 8));
            if (l15 == 0)
                atomicMin(&v0u[wm*32 + (i>>2)*16 + quad*4 + (i&3)], __float_as_uint(v));
        }
    };
    auto thr_reload = [&]() {
#pragma unroll
        for (int i = 0; i < 8; ++i)
            thr[i] = __uint_as_float(v0u[wm*32 + (i>>2)*16 + quad*4 + (i&3)]) + WWIN;
    };

    // ---- preview: chunk 0 (no appends) seeds the lagged threshold ----
    mfma_chunk(0, false);
    v0_commit();
    __syncthreads();
    thr_reload();

    // ---- main sweep: single buffer, register prefetch, 2 barriers/chunk ----
#pragma unroll 1
    for (int c = 0; c < NCHUNKS; ++c) {
        uint4 peh[2], pel[2];
        float e2p = 0.f;
        if (c + 1 < NCHUNKS) {
            const int nb = (c + 1) * NCH;
#pragma unroll
            for (int it = 0; it < 2; ++it) {
                int g = it * 512 + tid, rr = g >> 3, c8 = g & 7;
                peh[it] = ((const uint4*)(ehg + (size_t)(nb + rr) * DDIM))[c8];
                pel[it] = ((const uint4*)(elg + (size_t)(nb + rr) * DDIM))[c8];
            }
            if (tid < NCH) e2p = e2g[nb + tid];
        }
        mfma_chunk(c * NCH, true);
        __syncthreads();   // all reads of es done
        if (c + 1 < NCHUNKS) {
#pragma unroll
            for (int it = 0; it < 2; ++it) {
                int g = it * 512 + tid, rr = g >> 3, c8 = g & 7;
                *(uint4*)(&esh[rr * ESTR + c8 * 8]) = peh[it];
                *(uint4*)(&esl[rr * ESTR + c8 * 8]) = pel[it];
            }
            if (tid < NCH) e2t[tid] = e2p;
        }
        if (c & 1) v0_commit();
        __syncthreads();   // es ready / v0 visible
        if (c & 1) thr_reload();
    }

    // ---- Exact rescore (np chain), lexicographic (s, n) min per token ----
    int cnt = lcnt; if (cnt > LCAP) cnt = LCAP;
    for (int i = tid; i < cnt; i += 512) {
        unsigned e = list[i];
        int m = (int)(e >> 12), n = (int)(e & 4095u);
        const float* zrow = z + zbase + (size_t)m * DDIM;
        const float* erow = emb + (size_t)n * DDIM;
        float a = 0.f;
#pragma unroll
        for (int j = 0; j < DDIM; ++j) a = fmaf(zrow[j] + zrow[j], erow[j], a);
        float s = (z2s[m] + e2g[n]) - a;   // two fp32 roundings, exactly as np
        unsigned long long key = ((unsigned long long)__float_as_uint(s) << 32)
                               | (unsigned long long)(unsigned)n;
        atomicMin(&keys[m], key);
    }
    __syncthreads();

    if (tid < MB) {
        int nstar = (int)(keys[tid] & 0xffffffffULL);
        bidx_s[tid] = nstar;
        out[IDXOFF + tok0 + tid] = (float)nstar;
    }
    __syncthreads();

    // ---- Epilogue: quantized gather-write (coalesced float4) + loss ----
    float lsum = 0.f;
#pragma unroll
    for (int it = 0; it < 4; ++it) {
        int f  = it * 512 + tid;    // 0..2047 float4 slots
        int tt = f >> 4, cc = f & 15;
        int idx = bidx_s[tt];
        float4 qv = ((const float4*)(emb + (size_t)idx * DDIM))[cc];
        float4 zv = ((const float4*)(z + zbase))[f];
        ((float4*)(out + zbase))[f] = qv;
        float dx = qv.x - zv.x, dy = qv.y - zv.y;
        float dz = qv.z - zv.z, dw = qv.w - zv.w;
        lsum += dx * dx + dy * dy + dz * dz + dw * dw;
    }
    red[tid] = lsum;
    __syncthreads();
    for (int s = 256; s > 0; s >>= 1) {
        if (tid < s) red[tid] += red[tid + s];
        __syncthreads();
    }
    if (tid == 0) atomicAdd(lossacc, (double)red[0]);
}

__global__ void k_fin(const double* __restrict__ lossacc, float* __restrict__ out) {
    out[LOSSOFF] = (float)(2.0 * (*lossacc) / (double)(NTOK * DDIM));
}

extern "C" void kernel_launch(void* const* d_in, const int* in_sizes, int n_in,
                              void* d_out, int out_size, void* d_ws, size_t ws_size,
                              hipStream_t stream) {
    const float* z   = (const float*)d_in[0];   // [16,4096,64] fp32
    const float* emb = (const float*)d_in[1];   // [4096,64] fp32
    float* out = (float*)d_out;

    char* ws = (char*)d_ws;
    float*          e2g     = (float*)(ws);                    // 16 KB
    unsigned short* ehg     = (unsigned short*)(ws + 16384);   // 512 KB
    unsigned short* elg     = (unsigned short*)(ws + 540672);  // 512 KB
    double*         lossacc = (double*)(ws + 1064960);

    hipLaunchKernelGGL(k_prep, dim3(16), dim3(256), 0, stream, emb, e2g, ehg, elg, lossacc);
    hipLaunchKernelGGL(k_vq, dim3(NTOK / MB), dim3(512), 0, stream,
                       z, emb, e2g, ehg, elg, out, lossacc);
    hipLaunchKernelGGL(k_fin, dim3(1), dim3(1), 0, stream, lossacc, out);
}

// Round 10
// 288.241 us; speedup vs baseline: 1.3795x; 1.3795x over previous
//
#include <hip/hip_runtime.h>

// Problem constants
#define NTOK 65536          // B*S tokens
#define DDIM 64             // embedding dim
#define KCB  4096           // codebook size
#define MB   128            // tokens per block
#define NTILES 256          // 16-col tiles in codebook
#define TPW  64             // tiles per wave (wn quarter: 1024 codes)
#define LCAP 8192           // candidate capacity (expect ~2K)
#define WWIN 8.0e-5f        // >= 2*(|s-z2 vs h'| err ~1.2e-5)
#define IDXOFF  (NTOK * DDIM)
#define LOSSOFF (NTOK * DDIM + NTOK)

typedef __bf16 bf16x8 __attribute__((ext_vector_type(8)));
typedef float  f32x4  __attribute__((ext_vector_type(4)));

__device__ __forceinline__ float opaque(float x) { asm volatile("" : "+v"(x)); return x; }

// numpy pairwise sum of squares, n=64
__device__ __forceinline__ float np_sumsq64(const float* __restrict__ v) {
    float r[8];
#pragma unroll
    for (int j = 0; j < 8; ++j) r[j] = opaque(v[j] * v[j]);
#pragma unroll
    for (int i = 1; i < 8; ++i)
#pragma unroll
        for (int j = 0; j < 8; ++j) r[j] += opaque(v[8 * i + j] * v[8 * i + j]);
    return ((r[0] + r[1]) + (r[2] + r[3])) + ((r[4] + r[5]) + (r[6] + r[7]));
}

__device__ __forceinline__ unsigned short bf16rne(float x) {
    unsigned u = __float_as_uint(x);
    return (unsigned short)((u + 0x7fffu + ((u >> 16) & 1u)) >> 16);
}
__device__ __forceinline__ float bf16tof(unsigned short h) {
    return __uint_as_float(((unsigned)h) << 16);
}

// ---- Prep: e2 (np pairwise) + fragment-packed split-bf16 codebook ----
// pf[tile][sub][lane] (16B each): lane = quad*16+l15 gets
//   e_row[tile*16+l15][k = quad*8 + (sub&1)*32], sub 0/1 = high kh0/kh1, 2/3 = low.
__global__ void k_prep(const float* __restrict__ emb, float* __restrict__ e2,
                       uint4* __restrict__ pf, double* __restrict__ lossacc) {
    int k = blockIdx.x * blockDim.x + threadIdx.x;
    if (k == 0) *lossacc = 0.0;
    if (k >= KCB) return;
    float row[DDIM];
    const float4* r4 = (const float4*)(emb + (size_t)k * DDIM);
#pragma unroll
    for (int i = 0; i < DDIM / 4; ++i) {
        float4 v = r4[i];
        row[4*i+0] = v.x; row[4*i+1] = v.y; row[4*i+2] = v.z; row[4*i+3] = v.w;
    }
    e2[k] = np_sumsq64(row);
    unsigned short hr[DDIM], lr[DDIM];
#pragma unroll
    for (int j = 0; j < DDIM; ++j) {
        unsigned short h = bf16rne(row[j]);
        hr[j] = h;
        lr[j] = bf16rne(row[j] - bf16tof(h));
    }
    const int tile = k >> 4, rr = k & 15;
#pragma unroll
    for (int q = 0; q < 4; ++q) {
#pragma unroll
        for (int kh = 0; kh < 2; ++kh) {
            union { uint4 v; unsigned short s[8]; } th, tl;
#pragma unroll
            for (int j = 0; j < 8; ++j) {
                th.s[j] = hr[q*8 + kh*32 + j];
                tl.s[j] = lr[q*8 + kh*32 + j];
            }
            pf[(size_t)tile * 256 + (0 + kh) * 64 + q * 16 + rr] = th.v;
            pf[(size_t)tile * 256 + (2 + kh) * 64 + q * 16 + rr] = tl.v;
        }
    }
}

// ---- Main: barrier-free MFMA sweep over packed-global B + exact rescore ----
// 512 thr = 8 waves; wm = w>>2 (0..1): 64-token group; wn = w&3: 64-tile quarter.
// A = split-bf16(-2z) in VGPRs; acc init = e2[col]+0.5 -> MFMA emits
// h' = 0.5 + e2 - (2z).e directly. Capture h' <= thr (lagged min + W, shared
// via LDS atomicMin, NO barriers - monotone-min staleness is safe).
// Exact np-chain rescore of candidates -> lexicographic (s,n) = np argmin.
__global__ __launch_bounds__(512, 2)
void k_vq(const float* __restrict__ z, const float* __restrict__ emb,
          const float* __restrict__ e2g, const uint4* __restrict__ pf,
          float* __restrict__ out, double* __restrict__ lossacc) {
    __shared__ float e2t[KCB];               // 16 KB
    __shared__ float z2s[MB];
    __shared__ unsigned v0u[MB];
    __shared__ unsigned long long keys[MB];
    __shared__ unsigned list[LCAP];          // 32 KB
    __shared__ int lcnt;
    __shared__ float red[512];
    __shared__ int bidx_s[MB];

    const int tid  = threadIdx.x;
    const int lane = tid & 63;
    const int l15  = lane & 15;
    const int quad = lane >> 4;
    const int w    = tid >> 6;
    const int wm   = w >> 2;    // 0..1 : 64-token group
    const int wn   = w & 3;     // 0..3 : 64-tile quarter
    const int tok0 = blockIdx.x * MB;
    const size_t zbase = (size_t)tok0 * DDIM;

    if (tid < MB) { v0u[tid] = 0x7f800000u; keys[tid] = 0xFFFFFFFFFFFFFFFFull; }
    if (tid == 0) lcnt = 0;
    for (int i = tid; i < KCB; i += 512) e2t[i] = e2g[i];

    // ---- A-fragments: split bf16 of (-2z), global -> VGPRs (whole-kernel live) ----
    bf16x8 Ah[4][2], Al[4][2];   // [ms][kh]
#pragma unroll
    for (int ms = 0; ms < 4; ++ms) {
        const float* p = z + zbase + (size_t)(wm * 64 + ms * 16 + l15) * DDIM + quad * 8;
#pragma unroll
        for (int kh = 0; kh < 2; ++kh) {
            float4 u0 = *(const float4*)(p + kh * 32);
            float4 u1 = *(const float4*)(p + kh * 32 + 4);
            float d[8] = {-(u0.x + u0.x), -(u0.y + u0.y), -(u0.z + u0.z), -(u0.w + u0.w),
                          -(u1.x + u1.x), -(u1.y + u1.y), -(u1.z + u1.z), -(u1.w + u1.w)};
            union { bf16x8 v; unsigned short u[8]; } th, tl;
#pragma unroll
            for (int j = 0; j < 8; ++j) {
                unsigned short h = bf16rne(d[j]);
                th.u[j] = h;
                tl.u[j] = bf16rne(d[j] - bf16tof(h));
            }
            Ah[ms][kh] = th.v;
            Al[ms][kh] = tl.v;
        }
    }

    // z2 per token (exact np pairwise) — used only by the exact rescore
    if (tid < MB) {
        float row[DDIM];
        const float4* zr4 = (const float4*)(z + zbase + (size_t)tid * DDIM);
#pragma unroll
        for (int i = 0; i < DDIM / 4; ++i) {
            float4 v = zr4[i];
            row[4*i+0] = v.x; row[4*i+1] = v.y; row[4*i+2] = v.z; row[4*i+3] = v.w;
        }
        z2s[tid] = np_sumsq64(row);
    }
    __syncthreads();   // e2t/z2s/v0u/lcnt ready; NO barriers after this until rescore

    float thr[16];
#pragma unroll
    for (int i = 0; i < 16; ++i) thr[i] = 3.0e38f;

    auto do_tile = [&](int t, bool append) {
        const int tile = wn * TPW + t;
        const uint4* p = pf + (size_t)tile * 256 + lane;
        uint4 q0 = p[0], q1 = p[64], q2 = p[128], q3 = p[192];
        union { uint4 q; bf16x8 v; } b0, b1, b2, b3;
        b0.q = q0; b1.q = q1; b2.q = q2; b3.q = q3;   // Bh0,Bh1,Bl0,Bl1
        const int ncol = tile * 16 + l15;
        const float c0 = e2t[ncol] + 0.5f;
#pragma unroll
        for (int ms = 0; ms < 4; ++ms) {
            f32x4 a0 = {c0, c0, c0, c0}, a1 = {0.f, 0.f, 0.f, 0.f};
            a0 = __builtin_amdgcn_mfma_f32_16x16x32_bf16(Ah[ms][0], b0.v, a0, 0, 0, 0);
            a1 = __builtin_amdgcn_mfma_f32_16x16x32_bf16(Ah[ms][1], b1.v, a1, 0, 0, 0);
            a0 = __builtin_amdgcn_mfma_f32_16x16x32_bf16(Ah[ms][0], b2.v, a0, 0, 0, 0);
            a1 = __builtin_amdgcn_mfma_f32_16x16x32_bf16(Ah[ms][1], b3.v, a1, 0, 0, 0);
            a0 = __builtin_amdgcn_mfma_f32_16x16x32_bf16(Al[ms][0], b0.v, a0, 0, 0, 0);
            a1 = __builtin_amdgcn_mfma_f32_16x16x32_bf16(Al[ms][1], b1.v, a1, 0, 0, 0);
#pragma unroll
            for (int r = 0; r < 4; ++r) {
                const int i = ms * 4 + r;
                float h = a0[r] + a1[r];        // h' = 0.5 + e2 - m~
                if (append && h <= thr[i]) {
                    int m = wm * 64 + ms * 16 + quad * 4 + r;
                    int idx = atomicAdd(&lcnt, 1);
                    if (idx < LCAP) list[idx] = ((unsigned)m << 12) | (unsigned)ncol;
                }
                thr[i] = fminf(thr[i], h + WWIN);
            }
        }
    };
    auto commit_reload = [&]() {
#pragma unroll
        for (int i = 0; i < 16; ++i) {
            float v = thr[i] - WWIN;
            v = fminf(v, __shfl_xor(v, 1));
            v = fminf(v, __shfl_xor(v, 2));
            v = fminf(v, __shfl_xor(v, 4));
            v = fminf(v, __shfl_xor(v, 8));
            if (l15 == 0)
                atomicMin(&v0u[wm*64 + (i>>2)*16 + quad*4 + (i&3)], __float_as_uint(v));
        }
#pragma unroll
        for (int i = 0; i < 16; ++i) {
            float g = __uint_as_float(v0u[wm*64 + (i>>2)*16 + quad*4 + (i&3)]);
            thr[i] = fminf(thr[i], g + WWIN);
        }
    };

    // ---- preview (8 tiles, no appends) seeds thresholds block-wide ----
#pragma unroll 1
    for (int t = 0; t < 8; ++t) do_tile(t, false);
    commit_reload();

    // ---- main sweep: barrier-free; share mins every 8 tiles ----
#pragma unroll 1
    for (int g = 0; g < TPW / 8; ++g) {
#pragma unroll 1
        for (int tt = 0; tt < 8; ++tt) do_tile(g * 8 + tt, true);
        if (g + 1 < TPW / 8) commit_reload();
    }
    __syncthreads();   // list complete & visible

    // ---- Exact rescore (np chain), lexicographic (s, n) min per token ----
    int cnt = lcnt; if (cnt > LCAP) cnt = LCAP;
    for (int i = tid; i < cnt; i += 512) {
        unsigned e = list[i];
        int m = (int)(e >> 12), n = (int)(e & 4095u);
        const float* zrow = z + zbase + (size_t)m * DDIM;
        const float* erow = emb + (size_t)n * DDIM;
        float a = 0.f;
#pragma unroll
        for (int j = 0; j < DDIM; ++j) a = fmaf(zrow[j] + zrow[j], erow[j], a);
        float s = (z2s[m] + e2g[n]) - a;   // two fp32 roundings, exactly as np
        unsigned long long key = ((unsigned long long)__float_as_uint(s) << 32)
                               | (unsigned long long)(unsigned)n;
        atomicMin(&keys[m], key);
    }
    __syncthreads();

    if (tid < MB) {
        int nstar = (int)(keys[tid] & 0xffffffffULL);
        bidx_s[tid] = nstar;
        out[IDXOFF + tok0 + tid] = (float)nstar;
    }
    __syncthreads();

    // ---- Epilogue: quantized gather-write (coalesced float4) + loss ----
    float lsum = 0.f;
#pragma unroll
    for (int it = 0; it < 4; ++it) {
        int f  = it * 512 + tid;    // 0..2047 float4 slots
        int tt = f >> 4, cc = f & 15;
        int idx = bidx_s[tt];
        float4 qv = ((const float4*)(emb + (size_t)idx * DDIM))[cc];
        float4 zv = ((const float4*)(z + zbase))[f];
        ((float4*)(out + zbase))[f] = qv;
        float dx = qv.x - zv.x, dy = qv.y - zv.y;
        float dz = qv.z - zv.z, dw = qv.w - zv.w;
        lsum += dx * dx + dy * dy + dz * dz + dw * dw;
    }
    red[tid] = lsum;
    __syncthreads();
    for (int s = 256; s > 0; s >>= 1) {
        if (tid < s) red[tid] += red[tid + s];
        __syncthreads();
    }
    if (tid == 0) atomicAdd(lossacc, (double)red[0]);
}

__global__ void k_fin(const double* __restrict__ lossacc, float* __restrict__ out) {
    out[LOSSOFF] = (float)(2.0 * (*lossacc) / (double)(NTOK * DDIM));
}

extern "C" void kernel_launch(void* const* d_in, const int* in_sizes, int n_in,
                              void* d_out, int out_size, void* d_ws, size_t ws_size,
                              hipStream_t stream) {
    const float* z   = (const float*)d_in[0];   // [16,4096,64] fp32
    const float* emb = (const float*)d_in[1];   // [4096,64] fp32
    float* out = (float*)d_out;

    char* ws = (char*)d_ws;
    float*  e2g     = (float*)(ws);                 // 16 KB
    uint4*  pf      = (uint4*)(ws + 16384);         // 1 MB packed frags
    double* lossacc = (double*)(ws + 16384 + 1048576);

    hipLaunchKernelGGL(k_prep, dim3(16), dim3(256), 0, stream, emb, e2g, pf, lossacc);
    hipLaunchKernelGGL(k_vq, dim3(NTOK / MB), dim3(512), 0, stream,
                       z, emb, e2g, pf, out, lossacc);
    hipLaunchKernelGGL(k_fin, dim3(1), dim3(1), 0, stream, lossacc, out);
}

// Round 11
// 276.560 us; speedup vs baseline: 1.4378x; 1.0422x over previous
//
#include <hip/hip_runtime.h>

// Problem constants
#define NTOK 65536          // B*S tokens
#define DDIM 64             // embedding dim
#define KCB  4096           // codebook size
#define MB   128            // tokens per block
#define NTILES 256          // 16-col tiles in codebook
#define TPW  64             // tiles per wave (wn quarter: 1024 codes)
#define LCAP 8192           // candidate capacity (expect ~500)
#define WWIN 5.0e-4f        // >= 2*delta; delta <= 2.2e-4 (single-product worst case)
#define IDXOFF  (NTOK * DDIM)
#define LOSSOFF (NTOK * DDIM + NTOK)

typedef __bf16 bf16x8 __attribute__((ext_vector_type(8)));
typedef float  f32x4  __attribute__((ext_vector_type(4)));

__device__ __forceinline__ float opaque(float x) { asm volatile("" : "+v"(x)); return x; }

// numpy pairwise sum of squares, n=64
__device__ __forceinline__ float np_sumsq64(const float* __restrict__ v) {
    float r[8];
#pragma unroll
    for (int j = 0; j < 8; ++j) r[j] = opaque(v[j] * v[j]);
#pragma unroll
    for (int i = 1; i < 8; ++i)
#pragma unroll
        for (int j = 0; j < 8; ++j) r[j] += opaque(v[8 * i + j] * v[8 * i + j]);
    return ((r[0] + r[1]) + (r[2] + r[3])) + ((r[4] + r[5]) + (r[6] + r[7]));
}

__device__ __forceinline__ unsigned short bf16rne(float x) {
    unsigned u = __float_as_uint(x);
    return (unsigned short)((u + 0x7fffu + ((u >> 16) & 1u)) >> 16);
}

// ---- Prep: exact e2 (np pairwise) + fragment-packed bf16(high) codebook ----
// pfh[tile*128 + kh*64 + lane]: lane = quad*16+l15 holds
//   bf16(e_row[tile*16+l15][quad*8 + kh*32 .. +8])  (16 B = 8 bf16)
__global__ void k_prep(const float* __restrict__ emb, float* __restrict__ e2,
                       uint4* __restrict__ pfh, double* __restrict__ lossacc) {
    int k = blockIdx.x * blockDim.x + threadIdx.x;
    if (k == 0) *lossacc = 0.0;
    if (k >= KCB) return;
    float row[DDIM];
    const float4* r4 = (const float4*)(emb + (size_t)k * DDIM);
#pragma unroll
    for (int i = 0; i < DDIM / 4; ++i) {
        float4 v = r4[i];
        row[4*i+0] = v.x; row[4*i+1] = v.y; row[4*i+2] = v.z; row[4*i+3] = v.w;
    }
    e2[k] = np_sumsq64(row);
    const int tile = k >> 4, rr = k & 15;
#pragma unroll
    for (int q = 0; q < 4; ++q) {
#pragma unroll
        for (int kh = 0; kh < 2; ++kh) {
            union { uint4 v; unsigned short s[8]; } th;
#pragma unroll
            for (int j = 0; j < 8; ++j) th.s[j] = bf16rne(row[q*8 + kh*32 + j]);
            pfh[(size_t)tile * 128 + kh * 64 + q * 16 + rr] = th.v;
        }
    }
}

// ---- Main: barrier-free single-product MFMA sweep + exact np-chain rescore ----
// 512 thr = 8 waves; wm = w>>2 (0..1): 64-token group; wn = w&3: 64-tile quarter.
// A = bf16(-2z) in VGPRs; acc init 0.5 -> MFMA emits h = 0.5 - m^ directly
// (m^ approximates 2z.e to delta <= 2.2e-4; W = 5e-4 >= 2*delta).
// Capture h <= lagged_min + W via LDS atomicMin-shared thresholds (no barriers;
// monotone-min staleness only widens the captured superset).
// Exact rescore: s = fl(fl(z2+e2)-seqFMA(2z*e)) -> lex (s,n) = np argmin.
__global__ __launch_bounds__(512, 2)
void k_vq(const float* __restrict__ z, const float* __restrict__ emb,
          const float* __restrict__ e2g, const uint4* __restrict__ pfh,
          float* __restrict__ out, double* __restrict__ lossacc) {
    __shared__ float z2s[MB];
    __shared__ unsigned v0u[MB];
    __shared__ unsigned long long keys[MB];
    __shared__ unsigned list[LCAP];          // 32 KB
    __shared__ int lcnt;
    __shared__ float red[512];
    __shared__ int bidx_s[MB];

    const int tid  = threadIdx.x;
    const int lane = tid & 63;
    const int l15  = lane & 15;
    const int quad = lane >> 4;
    const int w    = tid >> 6;
    const int wm   = w >> 2;    // 0..1 : 64-token group
    const int wn   = w & 3;     // 0..3 : 64-tile quarter
    const int tok0 = blockIdx.x * MB;
    const size_t zbase = (size_t)tok0 * DDIM;

    if (tid < MB) { v0u[tid] = 0x7f800000u; keys[tid] = 0xFFFFFFFFFFFFFFFFull; }
    if (tid == 0) lcnt = 0;

    // ---- A-fragments: bf16(-2z), global -> VGPRs (whole-kernel live) ----
    bf16x8 Ah[4][2];   // [ms][kh]
#pragma unroll
    for (int ms = 0; ms < 4; ++ms) {
        const float* p = z + zbase + (size_t)(wm * 64 + ms * 16 + l15) * DDIM + quad * 8;
#pragma unroll
        for (int kh = 0; kh < 2; ++kh) {
            float4 u0 = *(const float4*)(p + kh * 32);
            float4 u1 = *(const float4*)(p + kh * 32 + 4);
            float d[8] = {-(u0.x + u0.x), -(u0.y + u0.y), -(u0.z + u0.z), -(u0.w + u0.w),
                          -(u1.x + u1.x), -(u1.y + u1.y), -(u1.z + u1.z), -(u1.w + u1.w)};
            union { bf16x8 v; unsigned short u[8]; } th;
#pragma unroll
            for (int j = 0; j < 8; ++j) th.u[j] = bf16rne(d[j]);
            Ah[ms][kh] = th.v;
        }
    }

    // z2 per token (exact np pairwise) — used only by the exact rescore
    if (tid < MB) {
        float row[DDIM];
        const float4* zr4 = (const float4*)(z + zbase + (size_t)tid * DDIM);
#pragma unroll
        for (int i = 0; i < DDIM / 4; ++i) {
            float4 v = zr4[i];
            row[4*i+0] = v.x; row[4*i+1] = v.y; row[4*i+2] = v.z; row[4*i+3] = v.w;
        }
        z2s[tid] = np_sumsq64(row);
    }
    __syncthreads();   // z2s/v0u/lcnt ready; NO barriers until rescore

    float thr[16];
#pragma unroll
    for (int i = 0; i < 16; ++i) thr[i] = 3.0e38f;

    const uint4* pbase = pfh + (size_t)(wn * TPW) * 128 + lane;

    auto compute = [&](uint4 q0, uint4 q1, int t, bool append) {
        union { uint4 q; bf16x8 v; } b0, b1;
        b0.q = q0; b1.q = q1;
        const int ncol = (wn * TPW + t) * 16 + l15;
#pragma unroll
        for (int ms = 0; ms < 4; ++ms) {
            f32x4 a = {0.5f, 0.5f, 0.5f, 0.5f};
            a = __builtin_amdgcn_mfma_f32_16x16x32_bf16(Ah[ms][0], b0.v, a, 0, 0, 0);
            a = __builtin_amdgcn_mfma_f32_16x16x32_bf16(Ah[ms][1], b1.v, a, 0, 0, 0);
#pragma unroll
            for (int r = 0; r < 4; ++r) {
                const int i = ms * 4 + r;
                float h = a[r];                 // h = 0.5 - m^
                if (append && h <= thr[i]) {
                    int m = wm * 64 + ms * 16 + quad * 4 + r;
                    int idx = atomicAdd(&lcnt, 1);
                    if (idx < LCAP) list[idx] = ((unsigned)m << 12) | (unsigned)ncol;
                }
                thr[i] = fminf(thr[i], h + WWIN);
            }
        }
    };
    auto commit_reload = [&]() {
#pragma unroll
        for (int i = 0; i < 16; ++i) {
            float v = thr[i] - WWIN;
            v = fminf(v, __shfl_xor(v, 1));
            v = fminf(v, __shfl_xor(v, 2));
            v = fminf(v, __shfl_xor(v, 4));
            v = fminf(v, __shfl_xor(v, 8));
            if (l15 == 0)
                atomicMin(&v0u[wm*64 + (i>>2)*16 + quad*4 + (i&3)], __float_as_uint(v));
        }
#pragma unroll
        for (int i = 0; i < 16; ++i) {
            float g = __uint_as_float(v0u[wm*64 + (i>>2)*16 + quad*4 + (i&3)]);
            thr[i] = fminf(thr[i], g + WWIN);
        }
    };

    // ---- preview (8 tiles, no appends) seeds thresholds block-wide ----
#pragma unroll 1
    for (int t = 0; t < 8; ++t)
        compute(pbase[(size_t)t * 128], pbase[(size_t)t * 128 + 64], t, false);
    commit_reload();

    // ---- main sweep: barrier-free, register prefetch, share mins every 8 tiles ----
    uint4 c0 = pbase[0], c1 = pbase[64];
#pragma unroll 1
    for (int t = 0; t < TPW; ++t) {
        uint4 n0, n1;
        if (t + 1 < TPW) {
            n0 = pbase[(size_t)(t + 1) * 128];
            n1 = pbase[(size_t)(t + 1) * 128 + 64];
        }
        compute(c0, c1, t, true);
        c0 = n0; c1 = n1;
        if ((t & 7) == 7 && t + 1 < TPW) commit_reload();
    }
    __syncthreads();   // list complete & visible

    // ---- Exact rescore (np chain), lexicographic (s, n) min per token ----
    int cnt = lcnt; if (cnt > LCAP) cnt = LCAP;
    for (int i = tid; i < cnt; i += 512) {
        unsigned e = list[i];
        int m = (int)(e >> 12), n = (int)(e & 4095u);
        const float* zrow = z + zbase + (size_t)m * DDIM;
        const float* erow = emb + (size_t)n * DDIM;
        float a = 0.f;
#pragma unroll
        for (int j = 0; j < DDIM; ++j) a = fmaf(zrow[j] + zrow[j], erow[j], a);
        float s = (z2s[m] + e2g[n]) - a;   // two fp32 roundings, exactly as np
        unsigned long long key = ((unsigned long long)__float_as_uint(s) << 32)
                               | (unsigned long long)(unsigned)n;
        atomicMin(&keys[m], key);
    }
    __syncthreads();

    if (tid < MB) {
        int nstar = (int)(keys[tid] & 0xffffffffULL);
        bidx_s[tid] = nstar;
        out[IDXOFF + tok0 + tid] = (float)nstar;
    }
    __syncthreads();

    // ---- Epilogue: quantized gather-write (coalesced float4) + loss ----
    float lsum = 0.f;
#pragma unroll
    for (int it = 0; it < 4; ++it) {
        int f  = it * 512 + tid;    // 0..2047 float4 slots
        int tt = f >> 4, cc = f & 15;
        int idx = bidx_s[tt];
        float4 qv = ((const float4*)(emb + (size_t)idx * DDIM))[cc];
        float4 zv = ((const float4*)(z + zbase))[f];
        ((float4*)(out + zbase))[f] = qv;
        float dx = qv.x - zv.x, dy = qv.y - zv.y;
        float dz = qv.z - zv.z, dw = qv.w - zv.w;
        lsum += dx * dx + dy * dy + dz * dz + dw * dw;
    }
    red[tid] = lsum;
    __syncthreads();
    for (int s = 256; s > 0; s >>= 1) {
        if (tid < s) red[tid] += red[tid + s];
        __syncthreads();
    }
    if (tid == 0) atomicAdd(lossacc, (double)red[0]);
}

__global__ void k_fin(const double* __restrict__ lossacc, float* __restrict__ out) {
    out[LOSSOFF] = (float)(2.0 * (*lossacc) / (double)(NTOK * DDIM));
}

extern "C" void kernel_launch(void* const* d_in, const int* in_sizes, int n_in,
                              void* d_out, int out_size, void* d_ws, size_t ws_size,
                              hipStream_t stream) {
    const float* z   = (const float*)d_in[0];   // [16,4096,64] fp32
    const float* emb = (const float*)d_in[1];   // [4096,64] fp32
    float* out = (float*)d_out;

    char* ws = (char*)d_ws;
    float*  e2g     = (float*)(ws);                 // 16 KB
    uint4*  pfh     = (uint4*)(ws + 16384);         // 512 KB packed high frags
    double* lossacc = (double*)(ws + 16384 + 524288);

    hipLaunchKernelGGL(k_prep, dim3(64), dim3(64), 0, stream, emb, e2g, pfh, lossacc);
    hipLaunchKernelGGL(k_vq, dim3(NTOK / MB), dim3(512), 0, stream,
                       z, emb, e2g, pfh, out, lossacc);
    hipLaunchKernelGGL(k_fin, dim3(1), dim3(1), 0, stream, lossacc, out);
}

// Round 12
// 213.740 us; speedup vs baseline: 1.8603x; 1.2939x over previous
//
#include <hip/hip_runtime.h>

// Problem constants
#define NTOK 65536          // B*S tokens
#define DDIM 64             // embedding dim
#define KCB  4096           // codebook size
#define MB   64             // tokens per block
#define NTILES 256          // 16-col tiles in codebook
#define TPW  64             // tiles per wave (wn quarter: 1024 codes)
#define LCAP 4096           // candidate capacity (expect ~500/block)
#define WWIN 5.0e-4f        // >= 2*delta; delta <= 2.2e-4 (single-product worst case)
#define IDXOFF  (NTOK * DDIM)
#define LOSSOFF (NTOK * DDIM + NTOK)

typedef __bf16 bf16x8 __attribute__((ext_vector_type(8)));
typedef float  f32x4  __attribute__((ext_vector_type(4)));

__device__ __forceinline__ float opaque(float x) { asm volatile("" : "+v"(x)); return x; }

// numpy pairwise sum of squares, n=64
__device__ __forceinline__ float np_sumsq64(const float* __restrict__ v) {
    float r[8];
#pragma unroll
    for (int j = 0; j < 8; ++j) r[j] = opaque(v[j] * v[j]);
#pragma unroll
    for (int i = 1; i < 8; ++i)
#pragma unroll
        for (int j = 0; j < 8; ++j) r[j] += opaque(v[8 * i + j] * v[8 * i + j]);
    return ((r[0] + r[1]) + (r[2] + r[3])) + ((r[4] + r[5]) + (r[6] + r[7]));
}

__device__ __forceinline__ unsigned short bf16rne(float x) {
    unsigned u = __float_as_uint(x);
    return (unsigned short)((u + 0x7fffu + ((u >> 16) & 1u)) >> 16);
}

// ---- Prep: exact e2 (np pairwise) + fragment-packed bf16(high) codebook ----
// pfh[tile*128 + kh*64 + lane]: lane = quad*16+l15 holds
//   bf16(e_row[tile*16+l15][quad*8 + kh*32 .. +8])  (16 B = 8 bf16)
__global__ void k_prep(const float* __restrict__ emb, float* __restrict__ e2,
                       uint4* __restrict__ pfh, double* __restrict__ lossacc) {
    int k = blockIdx.x * blockDim.x + threadIdx.x;
    if (k == 0) *lossacc = 0.0;
    if (k >= KCB) return;
    float row[DDIM];
    const float4* r4 = (const float4*)(emb + (size_t)k * DDIM);
#pragma unroll
    for (int i = 0; i < DDIM / 4; ++i) {
        float4 v = r4[i];
        row[4*i+0] = v.x; row[4*i+1] = v.y; row[4*i+2] = v.z; row[4*i+3] = v.w;
    }
    e2[k] = np_sumsq64(row);
    const int tile = k >> 4, rr = k & 15;
#pragma unroll
    for (int q = 0; q < 4; ++q) {
#pragma unroll
        for (int kh = 0; kh < 2; ++kh) {
            union { uint4 v; unsigned short s[8]; } th;
#pragma unroll
            for (int j = 0; j < 8; ++j) th.s[j] = bf16rne(row[q*8 + kh*32 + j]);
            pfh[(size_t)tile * 128 + kh * 64 + q * 16 + rr] = th.v;
        }
    }
}

// ---- Main: barrier-free single-product MFMA sweep + exact np-chain rescore ----
// 256 thr = 4 waves; wave wn covers a 64-tile quarter for ALL 64 block tokens
// (ms 0..3). A = bf16(-2z) in VGPRs; acc init 0.5 -> MFMA emits h = 0.5 - m^.
// Capture h <= lagged_min + W (LDS atomicMin-shared; staleness only widens the
// superset). Exact rescore: s = fl(fl(z2+e2)-seqFMA(2z*e)) -> lex (s,n).
__global__ __launch_bounds__(256, 4)
void k_vq(const float* __restrict__ z, const float* __restrict__ emb,
          const float* __restrict__ e2g, const uint4* __restrict__ pfh,
          float* __restrict__ out, double* __restrict__ lossacc) {
    __shared__ float z2s[MB];
    __shared__ unsigned v0u[MB];
    __shared__ unsigned long long keys[MB];
    __shared__ unsigned list[LCAP];          // 16 KB
    __shared__ int lcnt;
    __shared__ float red[256];
    __shared__ int bidx_s[MB];

    const int tid  = threadIdx.x;
    const int lane = tid & 63;
    const int l15  = lane & 15;
    const int quad = lane >> 4;
    const int wn   = tid >> 6;   // 0..3 : 64-tile quarter
    const int tok0 = blockIdx.x * MB;
    const size_t zbase = (size_t)tok0 * DDIM;

    if (tid < MB) { v0u[tid] = 0x7f800000u; keys[tid] = 0xFFFFFFFFFFFFFFFFull; }
    if (tid == 0) lcnt = 0;

    // ---- A-fragments: bf16(-2z), global -> VGPRs (whole-kernel live) ----
    bf16x8 Ah[4][2];   // [ms][kh]
#pragma unroll
    for (int ms = 0; ms < 4; ++ms) {
        const float* p = z + zbase + (size_t)(ms * 16 + l15) * DDIM + quad * 8;
#pragma unroll
        for (int kh = 0; kh < 2; ++kh) {
            float4 u0 = *(const float4*)(p + kh * 32);
            float4 u1 = *(const float4*)(p + kh * 32 + 4);
            float d[8] = {-(u0.x + u0.x), -(u0.y + u0.y), -(u0.z + u0.z), -(u0.w + u0.w),
                          -(u1.x + u1.x), -(u1.y + u1.y), -(u1.z + u1.z), -(u1.w + u1.w)};
            union { bf16x8 v; unsigned short u[8]; } th;
#pragma unroll
            for (int j = 0; j < 8; ++j) th.u[j] = bf16rne(d[j]);
            Ah[ms][kh] = th.v;
        }
    }

    // z2 per token (exact np pairwise) — used only by the exact rescore
    if (tid < MB) {
        float row[DDIM];
        const float4* zr4 = (const float4*)(z + zbase + (size_t)tid * DDIM);
#pragma unroll
        for (int i = 0; i < DDIM / 4; ++i) {
            float4 v = zr4[i];
            row[4*i+0] = v.x; row[4*i+1] = v.y; row[4*i+2] = v.z; row[4*i+3] = v.w;
        }
        z2s[tid] = np_sumsq64(row);
    }
    __syncthreads();   // z2s/v0u/lcnt ready; NO barriers until rescore

    float thr[16];
#pragma unroll
    for (int i = 0; i < 16; ++i) thr[i] = 3.0e38f;

    const uint4* pbase = pfh + (size_t)(wn * TPW) * 128 + lane;

    auto compute = [&](uint4 q0, uint4 q1, int t, bool append) {
        union { uint4 q; bf16x8 v; } b0, b1;
        b0.q = q0; b1.q = q1;
        const int ncol = (wn * TPW + t) * 16 + l15;
#pragma unroll
        for (int ms = 0; ms < 4; ++ms) {
            f32x4 a = {0.5f, 0.5f, 0.5f, 0.5f};
            a = __builtin_amdgcn_mfma_f32_16x16x32_bf16(Ah[ms][0], b0.v, a, 0, 0, 0);
            a = __builtin_amdgcn_mfma_f32_16x16x32_bf16(Ah[ms][1], b1.v, a, 0, 0, 0);
#pragma unroll
            for (int r = 0; r < 4; ++r) {
                const int i = ms * 4 + r;
                float h = a[r];                 // h = 0.5 - m^
                if (append) {
                    bool p = (h <= thr[i]);
                    if (__ballot(p)) {          // wave-uniform fast path
                        if (p) {
                            int m = ms * 16 + quad * 4 + r;
                            int idx = atomicAdd(&lcnt, 1);
                            if (idx < LCAP)
                                list[idx] = ((unsigned)m << 12) | (unsigned)ncol;
                        }
                    }
                }
                thr[i] = fminf(thr[i], h + WWIN);
            }
        }
    };
    auto commit_reload = [&]() {
#pragma unroll
        for (int i = 0; i < 16; ++i) {
            float v = thr[i] - WWIN;
            v = fminf(v, __shfl_xor(v, 1));
            v = fminf(v, __shfl_xor(v, 2));
            v = fminf(v, __shfl_xor(v, 4));
            v = fminf(v, __shfl_xor(v, 8));
            if (l15 == 0)
                atomicMin(&v0u[(i>>2)*16 + quad*4 + (i&3)], __float_as_uint(v));
        }
#pragma unroll
        for (int i = 0; i < 16; ++i) {
            float g = __uint_as_float(v0u[(i>>2)*16 + quad*4 + (i&3)]);
            thr[i] = fminf(thr[i], g + WWIN);
        }
    };

    // ---- preview (8 tiles, no appends) seeds thresholds block-wide ----
#pragma unroll 1
    for (int t = 0; t < 8; ++t)
        compute(pbase[(size_t)t * 128], pbase[(size_t)t * 128 + 64], t, false);
    commit_reload();

    // ---- main sweep: barrier-free, depth-2 prefetch, share mins every 8 tiles ----
    uint4 a0 = pbase[0],   a1 = pbase[64];
    uint4 b0 = pbase[128], b1 = pbase[192];
#pragma unroll 1
    for (int t = 0; t < TPW; t += 2) {
        uint4 c0, c1, d0, d1;
        if (t + 2 < TPW) {
            c0 = pbase[(size_t)(t + 2) * 128];
            c1 = pbase[(size_t)(t + 2) * 128 + 64];
            d0 = pbase[(size_t)(t + 3) * 128];
            d1 = pbase[(size_t)(t + 3) * 128 + 64];
        }
        compute(a0, a1, t, true);
        compute(b0, b1, t + 1, true);
        a0 = c0; a1 = c1; b0 = d0; b1 = d1;
        if ((t & 7) == 6 && t + 2 < TPW) commit_reload();
    }
    __syncthreads();   // list complete & visible

    // ---- Exact rescore (np chain), lexicographic (s, n) min per token ----
    int cnt = lcnt; if (cnt > LCAP) cnt = LCAP;
    for (int i = tid; i < cnt; i += 256) {
        unsigned e = list[i];
        int m = (int)(e >> 12), n = (int)(e & 4095u);
        const float* zrow = z + zbase + (size_t)m * DDIM;
        const float* erow = emb + (size_t)n * DDIM;
        float a = 0.f;
#pragma unroll
        for (int j = 0; j < DDIM; ++j) a = fmaf(zrow[j] + zrow[j], erow[j], a);
        float s = (z2s[m] + e2g[n]) - a;   // two fp32 roundings, exactly as np
        unsigned long long key = ((unsigned long long)__float_as_uint(s) << 32)
                               | (unsigned long long)(unsigned)n;
        atomicMin(&keys[m], key);
    }
    __syncthreads();

    if (tid < MB) {
        int nstar = (int)(keys[tid] & 0xffffffffULL);
        bidx_s[tid] = nstar;
        out[IDXOFF + tok0 + tid] = (float)nstar;
    }
    __syncthreads();

    // ---- Epilogue: quantized gather-write (coalesced float4) + loss ----
    float lsum = 0.f;
#pragma unroll
    for (int it = 0; it < 4; ++it) {
        int f  = it * 256 + tid;    // 0..1023 float4 slots (64 tok * 16)
        int tt = f >> 4, cc = f & 15;
        int idx = bidx_s[tt];
        float4 qv = ((const float4*)(emb + (size_t)idx * DDIM))[cc];
        float4 zv = ((const float4*)(z + zbase))[f];
        ((float4*)(out + zbase))[f] = qv;
        float dx = qv.x - zv.x, dy = qv.y - zv.y;
        float dz = qv.z - zv.z, dw = qv.w - zv.w;
        lsum += dx * dx + dy * dy + dz * dz + dw * dw;
    }
    red[tid] = lsum;
    __syncthreads();
    for (int s = 128; s > 0; s >>= 1) {
        if (tid < s) red[tid] += red[tid + s];
        __syncthreads();
    }
    if (tid == 0) atomicAdd(lossacc, (double)red[0]);
}

__global__ void k_fin(const double* __restrict__ lossacc, float* __restrict__ out) {
    out[LOSSOFF] = (float)(2.0 * (*lossacc) / (double)(NTOK * DDIM));
}

extern "C" void kernel_launch(void* const* d_in, const int* in_sizes, int n_in,
                              void* d_out, int out_size, void* d_ws, size_t ws_size,
                              hipStream_t stream) {
    const float* z   = (const float*)d_in[0];   // [16,4096,64] fp32
    const float* emb = (const float*)d_in[1];   // [4096,64] fp32
    float* out = (float*)d_out;

    char* ws = (char*)d_ws;
    float*  e2g     = (float*)(ws);                 // 16 KB
    uint4*  pfh     = (uint4*)(ws + 16384);         // 512 KB packed high frags
    double* lossacc = (double*)(ws + 16384 + 524288);

    hipLaunchKernelGGL(k_prep, dim3(64), dim3(64), 0, stream, emb, e2g, pfh, lossacc);
    hipLaunchKernelGGL(k_vq, dim3(NTOK / MB), dim3(256), 0, stream,
                       z, emb, e2g, pfh, out, lossacc);
    hipLaunchKernelGGL(k_fin, dim3(1), dim3(1), 0, stream, lossacc, out);
}